// Round 1
// baseline (202.413 us; speedup 1.0000x reference)
//
#include <hip/hip_runtime.h>

// Problem: B=8, S=512, NQ=12, L=4, 2^NQ = 4096 amplitudes.
// out = [psi_Q | psi_K | psi_V], each (B*S, 4096) fp32, concat flat.

#define BS_TOTAL 4096   // B*S = 8*512
#define NQ 12
#define NL 4
#define NSTATE 4096     // 2^12

__device__ __forceinline__ float2 cmul(float2 a, float2 b) {
    return make_float2(a.x * b.x - a.y * b.y, a.x * b.y + a.y * b.x);
}
__device__ __forceinline__ float2 cconj(float2 a) { return make_float2(a.x, -a.y); }
__device__ __forceinline__ float2 cadd(float2 a, float2 b) { return make_float2(a.x + b.x, a.y + b.y); }

// ---------------------------------------------------------------------------
// Pre-kernel: fold L=4 layers of Rz(a)Ry(b)Rz(c) into one 2x2 complex U per
// (matrix m in {Q,K,V}, qubit n). Output: Uout[(m*12+n)*4 + {00,01,10,11}].
// Tiny (36 lanes of work) — runs once per launch into d_ws.
// ---------------------------------------------------------------------------
__global__ void build_U(const float* __restrict__ tQ, const float* __restrict__ tK,
                        const float* __restrict__ tV, float2* __restrict__ Uout) {
    int t = threadIdx.x;
    if (t >= 36) return;
    int m = t / NQ, n = t % NQ;
    const float* th = (m == 0) ? tQ : (m == 1) ? tK : tV;   // (L, NQ, 3)
    float2 U00 = {1.f, 0.f}, U01 = {0.f, 0.f}, U10 = {0.f, 0.f}, U11 = {1.f, 0.f};
    for (int l = 0; l < NL; ++l) {
        float c = 0.5f * th[(l * NQ + n) * 3 + 0];  // inner Rz angle
        float b = 0.5f * th[(l * NQ + n) * 3 + 1];  // Ry angle
        float a = 0.5f * th[(l * NQ + n) * 3 + 2];  // outer Rz angle
        float sa, ca, sb, cb, sc, cc;
        sincosf(a, &sa, &ca);
        sincosf(b, &sb, &cb);
        sincosf(c, &sc, &cc);
        float2 ea = {ca, -sa};                 // exp(-i a)
        float2 ec = {cc, -sc};                 // exp(-i c)
        float2 p  = cmul(ea, ec);              // ea*ec
        float2 q  = cmul(ea, cconj(ec));       // ea*conj(ec)
        // Ul = Rz(a) @ Ry(b) @ Rz(c)
        float2 A00 = { cb * p.x,  cb * p.y};
        float2 A01 = {-sb * q.x, -sb * q.y};
        float2 A10 = { sb * q.x, -sb * q.y};   // sb * conj(q)
        float2 A11 = { cb * p.x, -cb * p.y};   // cb * conj(p)
        // U = Ul @ U
        float2 n00 = cadd(cmul(A00, U00), cmul(A01, U10));
        float2 n01 = cadd(cmul(A00, U01), cmul(A01, U11));
        float2 n10 = cadd(cmul(A10, U00), cmul(A11, U10));
        float2 n11 = cadd(cmul(A10, U01), cmul(A11, U11));
        U00 = n00; U01 = n01; U10 = n10; U11 = n11;
    }
    float2* o = Uout + (m * NQ + n) * 4;
    o[0] = U00; o[1] = U01; o[2] = U10; o[3] = U11;
}

// ---------------------------------------------------------------------------
// Main kernel: one block per (b,s); computes psi_Q/psi_K/psi_V (4096 fp32 each).
// Kron tree: vv (12 complex 2-vectors per matrix) -> groups of 4 qubits
// (AB[2][16] + Plo[16]) -> Phi[256] (qubits 0..7). state[k] = Re(Phi[k>>4] *
// Plo[k&15]); qubit q maps to bit (11-q) of k (reference kron order).
// ---------------------------------------------------------------------------
__global__ __launch_bounds__(256) void vqc_state_kernel(
    const float* __restrict__ angles,       // (B*S, 12)
    const float2* __restrict__ U,           // (3, 12, 4)
    float* __restrict__ out)                // (3, B*S, 4096)
{
    const int bs = blockIdx.x;              // 0 .. B*S-1
    const int t  = threadIdx.x;             // 0 .. 255

    __shared__ float  cs[NQ][2];            // cos/sin of angle/2 (shared by Q,K,V)
    __shared__ float2 vv[3][NQ][2];         // per-qubit 2-vectors
    __shared__ float2 AB[3][2][16];         // 4-qubit group products (qubits 0-3, 4-7)
    __shared__ float2 Plo[3][16];           // qubits 8-11
    __shared__ float2 Phi[3][256];          // qubits 0-7

    if (t < NQ) {
        float a = angles[bs * NQ + t];
        float s, c;
        sincosf(0.5f * a, &s, &c);
        cs[t][0] = c; cs[t][1] = s;
    }
    __syncthreads();

    if (t < 36) {
        int m = t / NQ, n = t % NQ;
        float c = cs[n][0], s = cs[n][1];
        const float2* u = U + (m * NQ + n) * 4;
        float2 u00 = u[0], u01 = u[1], u10 = u[2], u11 = u[3];
        vv[m][n][0] = make_float2(u00.x * c + u01.x * s, u00.y * c + u01.y * s);
        vv[m][n][1] = make_float2(u10.x * c + u11.x * s, u10.y * c + u11.y * s);
    }
    __syncthreads();

    // products over groups of 4 qubits: g=0 -> qubits 0-3, g=1 -> 4-7, g=2 -> 8-11
    if (t < 144) {
        int m = t / 48, r = t % 48, g = r / 16, idx = r % 16;
        int q0 = g * 4;
        float2 p = cmul(cmul(vv[m][q0    ][(idx >> 3) & 1],
                             vv[m][q0 + 1][(idx >> 2) & 1]),
                        cmul(vv[m][q0 + 2][(idx >> 1) & 1],
                             vv[m][q0 + 3][ idx       & 1]));
        if (g < 2) AB[m][g][idx] = p; else Plo[m][idx] = p;
    }
    __syncthreads();

#pragma unroll
    for (int m = 0; m < 3; ++m)
        Phi[m][t] = cmul(AB[m][0][t >> 4], AB[m][1][t & 15]);
    __syncthreads();

    // k = j*1024 + t*4 + i  (i=0..3): hi = k>>4 = j*64 + (t>>2), lo = 4*(t&3)+i
    const int lobase = 4 * (t & 3);
    const int hsub   = t >> 2;
#pragma unroll
    for (int m = 0; m < 3; ++m) {
        float2 l0 = Plo[m][lobase + 0];
        float2 l1 = Plo[m][lobase + 1];
        float2 l2 = Plo[m][lobase + 2];
        float2 l3 = Plo[m][lobase + 3];
        float* po = out + (size_t)m * BS_TOTAL * NSTATE + (size_t)bs * NSTATE;
#pragma unroll
        for (int j = 0; j < 4; ++j) {
            float2 h = Phi[m][j * 64 + hsub];
            float4 r;
            r.x = h.x * l0.x - h.y * l0.y;   // Re(h * l)
            r.y = h.x * l1.x - h.y * l1.y;
            r.z = h.x * l2.x - h.y * l2.y;
            r.w = h.x * l3.x - h.y * l3.y;
            *(float4*)(po + j * 1024 + t * 4) = r;
        }
    }
}

extern "C" void kernel_launch(void* const* d_in, const int* in_sizes, int n_in,
                              void* d_out, int out_size, void* d_ws, size_t ws_size,
                              hipStream_t stream) {
    (void)in_sizes; (void)n_in; (void)out_size; (void)ws_size;
    const float* angles = (const float*)d_in[0];   // (8,512,12)
    const float* tQ     = (const float*)d_in[1];   // (4,12,3)
    const float* tK     = (const float*)d_in[2];
    const float* tV     = (const float*)d_in[3];
    float2* Uws = (float2*)d_ws;                   // 36*4 float2 = 1152 B

    build_U<<<1, 64, 0, stream>>>(tQ, tK, tV, Uws);
    vqc_state_kernel<<<BS_TOTAL, 256, 0, stream>>>(angles, Uws, (float*)d_out);
}